// Round 7
// baseline (195.106 us; speedup 1.0000x reference)
//
#include <hip/hip_runtime.h>
#include <math.h>

#define NPTS 4096
#define EPSC 1e-5f
#define F2C (2.0f*1.44269504088896340736f)
#define SKIP_MARGIN 100.0f   // t < -100 -> weight < 2^-100 -> exactly 0 in fp32 sum

#if __has_builtin(__builtin_amdgcn_exp2f)
#define FEXP2 __builtin_amdgcn_exp2f
#else
#define FEXP2(x) __expf((x)*0.6931471805599453f)
#endif

#define IDX(i,j) ((i)*((i)+1)/2 + (j))   // packed lower-tri, i>=j

// one thread = one pc1 row; one block = (sample, 256-row block, CHN-col chunk)
// pc2 chunk staged in LDS. Two passes: (1) min-distance, (2) exp-accumulate with
// underflow-skip: columns with score < max-100 (log2) contribute exactly 0 in fp32.
template<int CHN>
__global__ void __launch_bounds__(256) k_soft(const float* __restrict__ pc1,
                                              const float* __restrict__ pc2,
                                              float* __restrict__ part){
  constexpr int NC = NPTS/CHN;
  int bid = blockIdx.x;
  int chunk = bid & (NC-1), rb = (bid/NC) & 15, b = bid/(NC*16);

  __shared__ float4 sp[CHN];                     // 8KB (CHN=512)
  {
    const float* p2 = pc2 + (size_t)b*4*NPTS + chunk*CHN;
    for (int m = threadIdx.x; m < CHN; m += 256){
      float x = p2[m], y = p2[m+NPTS], z = p2[m+2*NPTS];
      sp[m] = make_float4(x, y, z, x*x + y*y + z*z);
    }
  }
  __syncthreads();

  int n = rb*256 + threadIdx.x;
  const float* p1 = pc1 + (size_t)b*4*NPTS + n;
  float x1 = p1[0], y1 = p1[NPTS], z1 = p1[2*NPTS];
  float q1 = x1*x1 + y1*y1 + z1*z1;
  float mx = -2.f*x1, my = -2.f*y1, mz = -2.f*z1;

  // pass 1: chunk-min distance
  float dmin = 3.4e38f;
  #pragma unroll 8
  for (int m=0; m<CHN; ++m){
    float4 c = sp[m];
    float d = fmaf(mx,c.x, fmaf(my,c.y, fmaf(mz,c.z, c.w + q1)));
    dmin = fminf(dmin, d);
  }
  float m_ = F2C * __builtin_amdgcn_rcpf(fmaxf(dmin, EPSC));  // chunk max score (log2)
  float r  = m_ - SKIP_MARGIN;
  float d_thr = (r > 0.f) ? F2C * __builtin_amdgcn_rcpf(r) : 3.4e38f;

  // pass 2: accumulate, skipping guaranteed-underflow groups of 4
  float L=0.f, Ax=0.f, Ay=0.f, Az=0.f;
  for (int g=0; g<CHN; g+=4){
    float4 c0=sp[g], c1=sp[g+1], c2=sp[g+2], c3=sp[g+3];
    float d0 = fmaf(mx,c0.x, fmaf(my,c0.y, fmaf(mz,c0.z, c0.w + q1)));
    float d1 = fmaf(mx,c1.x, fmaf(my,c1.y, fmaf(mz,c1.z, c1.w + q1)));
    float d2 = fmaf(mx,c2.x, fmaf(my,c2.y, fmaf(mz,c2.z, c2.w + q1)));
    float d3 = fmaf(mx,c3.x, fmaf(my,c3.y, fmaf(mz,c3.z, c3.w + q1)));
    float gmin = fminf(fminf(d0,d1), fminf(d2,d3));
    if (__all(gmin > d_thr)) continue;            // all 64 rows: weight == 0.0f
    float p0 = FEXP2(fmaf(F2C, __builtin_amdgcn_rcpf(fmaxf(d0,EPSC)), -m_));
    float p1e= FEXP2(fmaf(F2C, __builtin_amdgcn_rcpf(fmaxf(d1,EPSC)), -m_));
    float p2e= FEXP2(fmaf(F2C, __builtin_amdgcn_rcpf(fmaxf(d2,EPSC)), -m_));
    float p3e= FEXP2(fmaf(F2C, __builtin_amdgcn_rcpf(fmaxf(d3,EPSC)), -m_));
    L += (p0+p1e)+(p2e+p3e);
    Ax = fmaf(p0,c0.x, fmaf(p1e,c1.x, fmaf(p2e,c2.x, fmaf(p3e,c3.x, Ax))));
    Ay = fmaf(p0,c0.y, fmaf(p1e,c1.y, fmaf(p2e,c2.y, fmaf(p3e,c3.y, Ay))));
    Az = fmaf(p0,c0.z, fmaf(p1e,c1.z, fmaf(p2e,c2.z, fmaf(p3e,c3.z, Az))));
  }
  float* pp = part + ((size_t)(b*NC + chunk)*5)*NPTS + n;
  pp[0]=m_; pp[NPTS]=L; pp[2*NPTS]=Ax; pp[3*NPTS]=Ay; pp[4*NPTS]=Az;
}

// merge chunk partials -> pc_nearest + dist; per-block partial stats sums.
// 512 threads: two 256-thread halves each merge NC/2 chunks, combine via LDS.
template<int NC>
__global__ void __launch_bounds__(512) k_merge(const float* __restrict__ pc1,
                                               const float* __restrict__ part,
                                               float* __restrict__ pcn,
                                               float* __restrict__ dist,
                                               float* __restrict__ psum13){
  int b = blockIdx.x >> 4, rb = blockIdx.x & 15;                    // 128 blocks
  int t = threadIdx.x & 255, half = threadIdx.x >> 8;
  int n = rb*256 + t;
  constexpr int H = NC/2;
  float sc[H], Lc[H], Axc[H], Ayc[H], Azc[H];
  float S = -3.4e38f;
  #pragma unroll
  for (int c=0;c<H;c++){
    const float* pp = part + ((size_t)(b*NC + half*H + c)*5)*NPTS + n;
    sc[c]=pp[0]; Lc[c]=pp[NPTS]; Axc[c]=pp[2*NPTS]; Ayc[c]=pp[3*NPTS]; Azc[c]=pp[4*NPTS];
    S = fmaxf(S, sc[c]);
  }
  float L=0.f, Ax=0.f, Ay=0.f, Az=0.f;
  #pragma unroll
  for (int c=0;c<H;c++){
    float w = FEXP2(sc[c]-S);
    L=fmaf(w,Lc[c],L); Ax=fmaf(w,Axc[c],Ax); Ay=fmaf(w,Ayc[c],Ay); Az=fmaf(w,Azc[c],Az);
  }
  __shared__ float ex[256][5];
  if (half==1){ ex[t][0]=S; ex[t][1]=L; ex[t][2]=Ax; ex[t][3]=Ay; ex[t][4]=Az; }
  __syncthreads();
  __shared__ float red[4][13];
  if (half==0){
    float S1=ex[t][0];
    float M = fmaxf(S,S1);
    float w0=FEXP2(S-M), w1=FEXP2(S1-M);
    L = w0*L + w1*ex[t][1];
    Ax = w0*Ax + w1*ex[t][2];
    Ay = w0*Ay + w1*ex[t][3];
    Az = w0*Az + w1*ex[t][4];
    float inv = 1.f/L;
    float px=Ax*inv, py=Ay*inv, pz=Az*inv;
    const float* p1 = pc1 + (size_t)b*4*NPTS + n;
    float x1=p1[0], y1=p1[NPTS], z1=p1[2*NPTS];
    float dx=x1-px, dy=y1-py, dz=z1-pz;
    float dd=sqrtf(dx*dx+dy*dy+dz*dz);
    pcn[(size_t)(b*3+0)*NPTS+n]=px;
    pcn[(size_t)(b*3+1)*NPTS+n]=py;
    pcn[(size_t)(b*3+2)*NPTS+n]=pz;
    dist[(size_t)b*NPTS+n]=dd;
    float acc[13]={x1,y1,z1,x1*x1,y1*y1,z1*z1,px,py,pz,px*px,py*py,pz*pz,dd};
    int lane = t & 63, wv = t >> 6;
    #pragma unroll
    for (int k=0;k<13;k++){
      float v = acc[k];
      v += __shfl_xor(v,32); v += __shfl_xor(v,16); v += __shfl_xor(v,8);
      v += __shfl_xor(v,4);  v += __shfl_xor(v,2);  v += __shfl_xor(v,1);
      if (lane==0) red[wv][k]=v;
    }
  }
  __syncthreads();
  if (threadIdx.x<13)
    psum13[(size_t)blockIdx.x*13 + threadIdx.x] =
      red[0][threadIdx.x]+red[1][threadIdx.x]+red[2][threadIdx.x]+red[3][threadIdx.x];
}

__device__ __forceinline__ void stats_from_tot(const float* stot, float* sst){
  const float Nf = 4096.f, Nm1 = 4095.f;
  #pragma unroll
  for (int j=0;j<3;j++){
    float m  = stot[j]/Nf;
    float v  = (stot[3+j]-Nf*m*m)/Nm1;             // ddof=1
    sst[j]=m; sst[3+j]=sqrtf(fmaxf(v,0.f));
    float m2 = stot[6+j]/Nf;
    float v2 = (stot[9+j]-Nf*m2*m2)/Nm1;
    sst[6+j]=m2; sst[9+j]=sqrtf(fmaxf(v2,0.f));
  }
  sst[12]=stot[12]/Nf;
}

// 64 blocks (8 slices x 8 samples): stats (redundant) + slice of the 40 weighted sums
__global__ void __launch_bounds__(256) k_acc(const float* __restrict__ pc1,
                                             const float* __restrict__ pcn,
                                             const float* __restrict__ dist,
                                             const float* __restrict__ psum13,
                                             float* __restrict__ psum40){
  int b = blockIdx.x >> 3, sl = blockIdx.x & 7, t = threadIdx.x;
  __shared__ float stot[13];
  __shared__ float sst[13];
  if (t<13){
    float s=0.f;
    #pragma unroll
    for (int i=0;i<16;i++) s += psum13[(size_t)(b*16+i)*13 + t];
    stot[t]=s;
  }
  __syncthreads();
  if (t==0) stats_from_tot(stot, sst);
  __syncthreads();
  float i1x=1.f/sst[3], i1y=1.f/sst[4], i1z=1.f/sst[5];
  float t1x=-sst[0]/sst[3], t1y=-sst[1]/sst[4], t1z=-sst[2]/sst[5];
  float i2x=1.f/sst[9], i2y=1.f/sst[10], i2z=1.f/sst[11];
  float t2x=-sst[6]/sst[9], t2y=-sst[7]/sst[10], t2z=-sst[8]/sst[11];
  float meanD=sst[12];

  float acc[40];
  #pragma unroll
  for (int k=0;k<40;k++) acc[k]=0.f;
  #pragma unroll
  for (int i=0;i<2;i++){
    int n = sl*512 + i*256 + t;
    const float* p1 = pc1 + (size_t)b*4*NPTS + n;
    float X1=fmaf(p1[0],i1x,t1x), Y1=fmaf(p1[NPTS],i1y,t1y), Z1=fmaf(p1[2*NPTS],i1z,t1z);
    float X2=fmaf(pcn[(size_t)(b*3+0)*NPTS+n],i2x,t2x);
    float Y2=fmaf(pcn[(size_t)(b*3+1)*NPTS+n],i2y,t2y);
    float Z2=fmaf(pcn[(size_t)(b*3+2)*NPTS+n],i2z,t2z);
    // sigmoid((dist-mean-EPS)*-1e10) > 0.5  <=>  (dist-mean)-EPS < 0
    float zthr = (dist[(size_t)b*NPTS+n] - meanD) - EPSC;
    float msk = (zthr < 0.f) ? 1.f : 0.f;
    float tz = msk*Z2;
    float wA = tz*Z2, wB = -tz*X2, wC = -tz*Y2;
    float wD = msk*fmaf(X2,X2,Y2*Y2);
    float ee[10]={X1*X1, X1*Y1, X1*Z1, X1, Y1*Y1, Y1*Z1, Y1, Z1*Z1, Z1, 1.f};
    #pragma unroll
    for (int j=0;j<10;j++){
      acc[j]    = fmaf(wA,ee[j],acc[j]);
      acc[10+j] = fmaf(wB,ee[j],acc[10+j]);
      acc[20+j] = fmaf(wC,ee[j],acc[20+j]);
      acc[30+j] = fmaf(wD,ee[j],acc[30+j]);
    }
  }
  __shared__ float red[4][40];
  {
    int lane=t&63, wv=t>>6;
    #pragma unroll
    for (int k=0;k<40;k++){
      float v=acc[k];
      v+=__shfl_xor(v,32); v+=__shfl_xor(v,16); v+=__shfl_xor(v,8);
      v+=__shfl_xor(v,4);  v+=__shfl_xor(v,2);  v+=__shfl_xor(v,1);
      if(lane==0) red[wv][k]=v;
    }
  }
  __syncthreads();
  if (t<40) psum40[(size_t)blockIdx.x*40 + t] = red[0][t]+red[1][t]+red[2][t]+red[3][t];
}

__device__ __forceinline__ float elemA(const float* S, int i, int k){
  int bi=i>>2, bj=k>>2;
  int ii=i&3, jj=k&3;
  int lo = ii<jj?ii:jj, hi = ii<jj?jj:ii;
  int pe = 4*lo - ((lo*(lo-1))>>1) + (hi-lo);        // sym 4x4 -> 10 idx
  int w;
  if (bi==bj) w = (bi==2)?30:0;
  else {
    int blo = bi<bj?bi:bj, bhi = bi<bj?bj:bi;
    if (blo==0 && bhi==1) return 0.f;                // A01 block is zero
    w = (blo==0)?10:20;                              // (0,2)->wB, (1,2)->wC
  }
  return S[w+pe];
}

// 8 blocks x 1 wave: reduce psum40, register Cholesky inverse-power eigensolve, compose
__global__ void __launch_bounds__(64) k_fin(const float* __restrict__ psum13,
                                            const float* __restrict__ psum40,
                                            float* __restrict__ out){
  int b=blockIdx.x, t=threadIdx.x;
  __shared__ float SS[40];
  __shared__ float stot[13];
  __shared__ float sst[13];
  if (t<40){
    float s=0.f;
    #pragma unroll
    for (int i=0;i<8;i++) s += psum40[(size_t)(b*8+i)*40 + t];
    SS[t]=s;
  }
  if (t<13){
    float s=0.f;
    #pragma unroll
    for (int i=0;i<16;i++) s += psum13[(size_t)(b*16+i)*13 + t];
    stot[t]=s;
  }
  __syncthreads();
  if (t==0) stats_from_tot(stot, sst);
  __syncthreads();

  // packed A (lower-tri), ridge, Cholesky — redundant across lanes
  float a[78];
  #pragma unroll
  for (int i=0;i<12;i++)
    #pragma unroll
    for (int j=0;j<=i;j++)
      a[IDX(i,j)] = elemA(SS,i,j);
  {
    float tr=0.f;
    #pragma unroll
    for (int i=0;i<12;i++) tr += a[IDX(i,i)];
    float eps = 1e-5f * tr * (1.f/12.f);             // uniform shift: eigvecs unchanged
    #pragma unroll
    for (int i=0;i<12;i++) a[IDX(i,i)] += eps;
  }
  #pragma unroll
  for (int j=0;j<12;j++){
    float s = a[IDX(j,j)];
    #pragma unroll
    for (int k=0;k<j;k++) s = fmaf(-a[IDX(j,k)], a[IDX(j,k)], s);
    float d = sqrtf(fmaxf(s, 1e-30f));
    a[IDX(j,j)] = d;
    float dinv = __builtin_amdgcn_rcpf(d);
    #pragma unroll
    for (int i=j+1;i<12;i++){
      float s2 = a[IDX(i,j)];
      #pragma unroll
      for (int k=0;k<j;k++) s2 = fmaf(-a[IDX(i,k)], a[IDX(j,k)], s2);
      a[IDX(i,j)] = s2 * dinv;
    }
  }
  // lane j: solve (A+eps I) x = e_j -> column j of B (lanes >=12 produce 0 rows)
  float y[12], Brow[12];
  #pragma unroll
  for (int i=0;i<12;i++){
    float s = (i==t) ? 1.f : 0.f;
    #pragma unroll
    for (int k=0;k<i;k++) s = fmaf(-a[IDX(i,k)], y[k], s);
    y[i] = s * __builtin_amdgcn_rcpf(a[IDX(i,i)]);
  }
  #pragma unroll
  for (int i=11;i>=0;i--){
    float s = y[i];
    #pragma unroll
    for (int k=11;k>i;k--) s = fmaf(-a[IDX(k,i)], Brow[k], s);
    Brow[i] = s * __builtin_amdgcn_rcpf(a[IDX(i,i)]);
  }
  {
    float mxv = 0.f;
    #pragma unroll
    for (int i=0;i<12;i++) mxv = fmaxf(mxv, fabsf(Brow[i]));
    mxv = fmaxf(mxv, __shfl_xor(mxv,1)); mxv = fmaxf(mxv, __shfl_xor(mxv,2));
    mxv = fmaxf(mxv, __shfl_xor(mxv,4)); mxv = fmaxf(mxv, __shfl_xor(mxv,8));
    float sc = __builtin_amdgcn_rcpf(mxv);
    #pragma unroll
    for (int i=0;i<12;i++) Brow[i] *= sc;
  }
  #pragma unroll
  for (int rep=0; rep<2; ++rep){                     // B -> B^2 -> B^4
    float nr[12];
    #pragma unroll
    for (int i=0;i<12;i++) nr[i]=0.f;
    #pragma unroll
    for (int k=0;k<12;k++){
      float bjk = Brow[k];
      #pragma unroll
      for (int m2=0;m2<12;m2++){
        float bkm = __shfl(Brow[m2], k);
        nr[m2] = fmaf(bjk, bkm, nr[m2]);
      }
    }
    float mxv = 0.f;
    #pragma unroll
    for (int i=0;i<12;i++) mxv = fmaxf(mxv, fabsf(nr[i]));
    mxv = fmaxf(mxv, __shfl_xor(mxv,1)); mxv = fmaxf(mxv, __shfl_xor(mxv,2));
    mxv = fmaxf(mxv, __shfl_xor(mxv,4)); mxv = fmaxf(mxv, __shfl_xor(mxv,8));
    float sc = __builtin_amdgcn_rcpf(mxv);
    #pragma unroll
    for (int i=0;i<12;i++) Brow[i] = nr[i]*sc;
  }
  float v = 0.f;
  #pragma unroll
  for (int i=0;i<12;i++) v += Brow[i];
  #pragma unroll
  for (int it=0; it<14; ++it){
    float w = 0.f;
    #pragma unroll
    for (int k=0;k<12;k++) w = fmaf(Brow[k], __shfl(v,k), w);
    float nn = w*w;
    nn += __shfl_xor(nn,1); nn += __shfl_xor(nn,2);
    nn += __shfl_xor(nn,4); nn += __shfl_xor(nn,8);
    v = w * rsqrtf(nn);
  }
  float pvf[12];
  #pragma unroll
  for (int i=0;i<12;i++) pvf[i] = __shfl(v, i);

  if (t==0){
    double pv[12];
    #pragma unroll
    for (int i=0;i<12;i++) pv[i]=(double)pvf[i];
    if (pv[10]<0.0){
      #pragma unroll
      for (int i=0;i<12;i++) pv[i]=-pv[i];
    }
    double nrm = sqrt(pv[8]*pv[8]+pv[9]*pv[9]+pv[10]*pv[10]);
    #pragma unroll
    for (int i=0;i<12;i++) pv[i]/=nrm;
    double m1[3]={sst[0],sst[1],sst[2]}, sd1[3]={sst[3],sst[4],sst[5]};
    double m2[3]={sst[6],sst[7],sst[8]}, sd2[3]={sst[9],sst[10],sst[11]};
    double Td[3][4]={{pv[0],pv[1],pv[2],pv[3]},
                     {pv[4],pv[5],pv[6],pv[7]},
                     {pv[8],pv[9],pv[10],pv[11]}};
    double F[3][4];
    for (int i=0;i<3;i++){
      double b3 = Td[i][3];
      for (int j=0;j<3;j++){
        F[i][j] = sd2[i]*(Td[i][j]/sd1[j]);          // inv(T2) @ Tdlt @ T1
        b3 += Td[i][j]*(-m1[j]/sd1[j]);
      }
      F[i][3] = sd2[i]*b3 + m2[i];
    }
    double zx=F[0][2],zy=F[1][2],zz2=F[2][2];
    double zn=sqrt(zx*zx+zy*zy+zz2*zz2);
    zx/=zn; zy/=zn; zz2/=zn;
    double yx=F[0][1],yy=F[1][1],yz=F[2][1];
    double xx=yy*zz2-yz*zy, xy=yz*zx-yx*zz2, xz=yx*zy-yy*zx;
    double xn=sqrt(xx*xx+xy*xy+xz*xz);
    xx/=xn; xy/=xn; xz/=xn;
    double y2x=zy*xz-zz2*xy, y2y=zz2*xx-zx*xz, y2z=zx*xy-zy*xx;
    double R00=xx,R01=y2x,R02=zx;
    double R10=xy,R11=y2y,R12=zy;
    double R20=xz,R21=y2z,R22=zz2;
    float* oT = out + b*16;
    oT[0]=(float)R00; oT[1]=(float)R01; oT[2]=(float)R02; oT[3]=(float)F[0][3];
    oT[4]=(float)R10; oT[5]=(float)R11; oT[6]=(float)R12; oT[7]=(float)F[1][3];
    oT[8]=(float)R20; oT[9]=(float)R21; oT[10]=(float)R22; oT[11]=(float)F[2][3];
    oT[12]=0.f; oT[13]=0.f; oT[14]=0.f; oT[15]=1.f;
    double qw=0.5*sqrt(fmax(1e-12, 1.0+R00+R11+R22));
    double qx=0.5*sqrt(fmax(0.0, 1.0+R00-R11-R22));
    double qy=0.5*sqrt(fmax(0.0, 1.0-R00+R11-R22));
    double qz=0.5*sqrt(fmax(0.0, 1.0-R00-R11+R22));
    if (R21-R12<0.0) qx=-qx;
    if (R02-R20<0.0) qy=-qy;
    if (R10-R01<0.0) qz=-qz;
    float* oQ = out + 128 + b*4;
    oQ[0]=(float)qw; oQ[1]=(float)qx; oQ[2]=(float)qy; oQ[3]=(float)qz;
    float* ot3 = out + 160 + b*3;
    ot3[0]=(float)F[0][3]; ot3[1]=(float)F[1][3]; ot3[2]=(float)F[2][3];
  }
}

extern "C" void kernel_launch(void* const* d_in, const int* in_sizes, int n_in,
                              void* d_out, int out_size, void* d_ws, size_t ws_size,
                              hipStream_t stream) {
  const float* pc1 = (const float*)d_in[0];
  const float* pc2 = (const float*)d_in[1];
  float* out  = (float*)d_out;
  float* ws   = (float*)d_ws;

  // NC=8 fixed: part 8*8*5*4096 = 1310720 floats (~5.9 MB total; proven fits)
  float* part  = ws;
  float* pcn   = part + 1310720;                     // 98304
  float* dist  = pcn + 98304;                        // 32768
  float* psum13= dist + 32768;                       // 128*13 = 1664
  float* psum40= psum13 + 1664;                      // 64*40 = 2560

  hipLaunchKernelGGL(k_soft<512>, dim3(1024), dim3(256), 0, stream, pc1, pc2, part);
  hipLaunchKernelGGL(k_merge<8>,  dim3(128),  dim3(512), 0, stream, pc1, part, pcn, dist, psum13);
  hipLaunchKernelGGL(k_acc,       dim3(64),   dim3(256), 0, stream, pc1, pcn, dist, psum13, psum40);
  hipLaunchKernelGGL(k_fin,       dim3(8),    dim3(64),  0, stream, psum13, psum40, out);
}

// Round 8
// 170.718 us; speedup vs baseline: 1.1429x; 1.1429x over previous
//
#include <hip/hip_runtime.h>
#include <math.h>

#define NPTS 4096
#define EPSC 1e-5f
#define F2C (2.0f*1.44269504088896340736f)

#if __has_builtin(__builtin_amdgcn_exp2f)
#define FEXP2 __builtin_amdgcn_exp2f
#else
#define FEXP2(x) __expf((x)*0.6931471805599453f)
#endif

#define IDX(i,j) ((i)*((i)+1)/2 + (j))   // packed lower-tri, i>=j

// one thread = one pc1 row; one block = (sample, 256-row block, 256-col chunk)
// pc2 chunk staged in LDS; ONLINE softmax (single pass, deferred per-wave rescale).
// Partials: float4(m,L,Ax,Ay) + float(Az) per (chunk,row).
__global__ void __launch_bounds__(256) k_soft(const float* __restrict__ pc1,
                                              const float* __restrict__ pc2,
                                              float4* __restrict__ part4,
                                              float* __restrict__ partZ){
  constexpr int CHN = 256, NC = 16;
  int bid = blockIdx.x;                          // 2048 blocks
  int chunk = bid & (NC-1), rb = (bid/NC) & 15, b = bid/(NC*16);

  __shared__ float4 sp[CHN];                     // 4KB
  {
    const float* p2 = pc2 + (size_t)b*4*NPTS + chunk*CHN;
    for (int m = threadIdx.x; m < CHN; m += 256){
      float x = p2[m], y = p2[m+NPTS], z = p2[m+2*NPTS];
      sp[m] = make_float4(x, y, z, x*x + y*y + z*z);
    }
  }
  __syncthreads();

  int n = rb*256 + threadIdx.x;
  const float* p1 = pc1 + (size_t)b*4*NPTS + n;
  float x1 = p1[0], y1 = p1[NPTS], z1 = p1[2*NPTS];
  float q1 = x1*x1 + y1*y1 + z1*z1;
  float mx = -2.f*x1, my = -2.f*y1, mz = -2.f*z1;

  // peel column 0
  float4 c0 = sp[0];
  float d0 = fmaf(mx,c0.x, fmaf(my,c0.y, fmaf(mz,c0.z, c0.w + q1)));
  float m_ = F2C * __builtin_amdgcn_rcpf(fmaxf(d0, EPSC));   // running max (log2 units)
  float L = 1.f, Ax = c0.x, Ay = c0.y, Az = c0.z;

  #pragma unroll 8
  for (int mm=1; mm<CHN; ++mm){
    float4 c = sp[mm];
    float d = fmaf(mx,c.x, fmaf(my,c.y, fmaf(mz,c.z, c.w + q1)));
    float dinv = __builtin_amdgcn_rcpf(fmaxf(d, EPSC));
    float t = fmaf(F2C, dinv, -m_);              // s - m
    if (__any(t > 0.f)){                         // wave-uniform rescale (rare)
      float tp = fmaxf(t, 0.f);
      float sc = FEXP2(-tp);
      L *= sc; Ax *= sc; Ay *= sc; Az *= sc;
      m_ += tp;
      t = fminf(t, 0.f);                         // s - m_new
    }
    float pe = FEXP2(t);
    L += pe;
    Ax = fmaf(pe,c.x,Ax); Ay = fmaf(pe,c.y,Ay); Az = fmaf(pe,c.z,Az);
  }
  size_t idx = (size_t)(b*NC + chunk)*NPTS + n;
  part4[idx] = make_float4(m_, L, Ax, Ay);
  partZ[idx] = Az;
}

__device__ __forceinline__ void stats_from_tot(const float* stot, float* sst){
  const float Nf = 4096.f, Nm1 = 4095.f;
  #pragma unroll
  for (int j=0;j<3;j++){
    float m  = stot[j]/Nf;
    float v  = (stot[3+j]-Nf*m*m)/Nm1;             // ddof=1
    sst[j]=m; sst[3+j]=sqrtf(fmaxf(v,0.f));
    float m2 = stot[6+j]/Nf;
    float v2 = (stot[9+j]-Nf*m2*m2)/Nm1;
    sst[6+j]=m2; sst[9+j]=sqrtf(fmaxf(v2,0.f));
  }
  sst[12]=stot[12]/Nf;
}

__device__ __forceinline__ float elemA(const float* S, int i, int k){
  int bi=i>>2, bj=k>>2;
  int ii=i&3, jj=k&3;
  int lo = ii<jj?ii:jj, hi = ii<jj?jj:ii;
  int pe = 4*lo - ((lo*(lo-1))>>1) + (hi-lo);        // sym 4x4 -> 10 idx
  int w;
  if (bi==bj) w = (bi==2)?30:0;
  else {
    int blo = bi<bj?bi:bj, bhi = bi<bj?bj:bi;
    if (blo==0 && bhi==1) return 0.f;                // A01 block is zero
    w = (blo==0)?10:20;                              // (0,2)->wB, (1,2)->wC
  }
  return S[w+pe];
}

// ONE kernel for the whole tail: 8 blocks (one per sample) x 512 threads.
// Phase A: merge 16 chunk-partials per row -> (px,py,pz,dd) in LDS + 13 stats sums.
// Phase B: stats -> masked M^T M 40-sums -> block reduce.
// Phase C: wave 0 register Cholesky inverse-power eigensolve + compose + outputs.
__global__ void __launch_bounds__(512) k_tail(const float* __restrict__ pc1,
                                              const float4* __restrict__ part4,
                                              const float* __restrict__ partZ,
                                              float* __restrict__ out){
  constexpr int NC = 16;
  int b = blockIdx.x, t = threadIdx.x;
  int lane = t & 63, wv = t >> 6;                // 8 waves

  __shared__ float4 rowdat[NPTS];                // 64KB: px,py,pz,dd per row
  __shared__ float red13[8][13];
  __shared__ float red40[8][40];
  __shared__ float stot[13];
  __shared__ float sst[13];
  __shared__ float SS[40];

  // ---- Phase A ----
  float acc13[13];
  #pragma unroll
  for (int k=0;k<13;k++) acc13[k]=0.f;
  for (int i=0;i<8;i++){
    int n = i*512 + t;
    float4 f[NC]; float zz[NC];
    #pragma unroll
    for (int c=0;c<NC;c++){
      size_t idx = (size_t)(b*NC + c)*NPTS + n;
      f[c]  = part4[idx];
      zz[c] = partZ[idx];
    }
    float S = f[0].x;
    #pragma unroll
    for (int c=1;c<NC;c++) S = fmaxf(S, f[c].x);
    float L=0.f, Ax=0.f, Ay=0.f, Az=0.f;
    #pragma unroll
    for (int c=0;c<NC;c++){
      float w = FEXP2(f[c].x - S);
      L  = fmaf(w, f[c].y, L);
      Ax = fmaf(w, f[c].z, Ax);
      Ay = fmaf(w, f[c].w, Ay);
      Az = fmaf(w, zz[c],  Az);
    }
    float inv = 1.f/L;
    float px=Ax*inv, py=Ay*inv, pz=Az*inv;
    const float* p1 = pc1 + (size_t)b*4*NPTS + n;
    float x1=p1[0], y1=p1[NPTS], z1=p1[2*NPTS];
    float dx=x1-px, dy=y1-py, dz=z1-pz;
    float dd=sqrtf(dx*dx+dy*dy+dz*dz);
    rowdat[n] = make_float4(px,py,pz,dd);
    acc13[0]+=x1;    acc13[1]+=y1;    acc13[2]+=z1;
    acc13[3]+=x1*x1; acc13[4]+=y1*y1; acc13[5]+=z1*z1;
    acc13[6]+=px;    acc13[7]+=py;    acc13[8]+=pz;
    acc13[9]+=px*px; acc13[10]+=py*py; acc13[11]+=pz*pz;
    acc13[12]+=dd;
  }
  #pragma unroll
  for (int k=0;k<13;k++){
    float v = acc13[k];
    v += __shfl_xor(v,32); v += __shfl_xor(v,16); v += __shfl_xor(v,8);
    v += __shfl_xor(v,4);  v += __shfl_xor(v,2);  v += __shfl_xor(v,1);
    if (lane==0) red13[wv][k]=v;
  }
  __syncthreads();
  if (t<13){
    float s=0.f;
    #pragma unroll
    for (int w=0;w<8;w++) s += red13[w][t];
    stot[t]=s;
  }
  __syncthreads();
  if (t==0) stats_from_tot(stot, sst);
  __syncthreads();

  // ---- Phase B ----
  float i1x=1.f/sst[3], i1y=1.f/sst[4], i1z=1.f/sst[5];
  float t1x=-sst[0]/sst[3], t1y=-sst[1]/sst[4], t1z=-sst[2]/sst[5];
  float i2x=1.f/sst[9], i2y=1.f/sst[10], i2z=1.f/sst[11];
  float t2x=-sst[6]/sst[9], t2y=-sst[7]/sst[10], t2z=-sst[8]/sst[11];
  float meanD=sst[12];

  float acc[40];
  #pragma unroll
  for (int k=0;k<40;k++) acc[k]=0.f;
  for (int i=0;i<8;i++){
    int n = i*512 + t;
    const float* p1 = pc1 + (size_t)b*4*NPTS + n;
    float X1=fmaf(p1[0],i1x,t1x), Y1=fmaf(p1[NPTS],i1y,t1y), Z1=fmaf(p1[2*NPTS],i1z,t1z);
    float4 rd = rowdat[n];
    float X2=fmaf(rd.x,i2x,t2x);
    float Y2=fmaf(rd.y,i2y,t2y);
    float Z2=fmaf(rd.z,i2z,t2z);
    // sigmoid((dist-mean-EPS)*-1e10) > 0.5  <=>  (dist-mean)-EPS < 0
    float zthr = (rd.w - meanD) - EPSC;
    float msk = (zthr < 0.f) ? 1.f : 0.f;
    float tz = msk*Z2;
    float wA = tz*Z2, wB = -tz*X2, wC = -tz*Y2;
    float wD = msk*fmaf(X2,X2,Y2*Y2);
    float ee[10]={X1*X1, X1*Y1, X1*Z1, X1, Y1*Y1, Y1*Z1, Y1, Z1*Z1, Z1, 1.f};
    #pragma unroll
    for (int j=0;j<10;j++){
      acc[j]    = fmaf(wA,ee[j],acc[j]);
      acc[10+j] = fmaf(wB,ee[j],acc[10+j]);
      acc[20+j] = fmaf(wC,ee[j],acc[20+j]);
      acc[30+j] = fmaf(wD,ee[j],acc[30+j]);
    }
  }
  #pragma unroll
  for (int k=0;k<40;k++){
    float v=acc[k];
    v+=__shfl_xor(v,32); v+=__shfl_xor(v,16); v+=__shfl_xor(v,8);
    v+=__shfl_xor(v,4);  v+=__shfl_xor(v,2);  v+=__shfl_xor(v,1);
    if(lane==0) red40[wv][k]=v;
  }
  __syncthreads();
  if (t<40){
    float s=0.f;
    #pragma unroll
    for (int w=0;w<8;w++) s += red40[w][t];
    SS[t]=s;
  }
  __syncthreads();

  // ---- Phase C: wave 0 ----
  if (t<64){
    float a[78];
    #pragma unroll
    for (int i=0;i<12;i++)
      #pragma unroll
      for (int j=0;j<=i;j++)
        a[IDX(i,j)] = elemA(SS,i,j);
    {
      float tr=0.f;
      #pragma unroll
      for (int i=0;i<12;i++) tr += a[IDX(i,i)];
      float eps = 1e-5f * tr * (1.f/12.f);           // uniform shift: eigvecs unchanged
      #pragma unroll
      for (int i=0;i<12;i++) a[IDX(i,i)] += eps;
    }
    #pragma unroll
    for (int j=0;j<12;j++){
      float s = a[IDX(j,j)];
      #pragma unroll
      for (int k=0;k<j;k++) s = fmaf(-a[IDX(j,k)], a[IDX(j,k)], s);
      float d = sqrtf(fmaxf(s, 1e-30f));
      a[IDX(j,j)] = d;
      float dinv = __builtin_amdgcn_rcpf(d);
      #pragma unroll
      for (int i=j+1;i<12;i++){
        float s2 = a[IDX(i,j)];
        #pragma unroll
        for (int k=0;k<j;k++) s2 = fmaf(-a[IDX(i,k)], a[IDX(j,k)], s2);
        a[IDX(i,j)] = s2 * dinv;
      }
    }
    // lane j: solve (A+eps I) x = e_j -> column j of B
    float y[12], Brow[12];
    #pragma unroll
    for (int i=0;i<12;i++){
      float s = (i==t) ? 1.f : 0.f;
      #pragma unroll
      for (int k=0;k<i;k++) s = fmaf(-a[IDX(i,k)], y[k], s);
      y[i] = s * __builtin_amdgcn_rcpf(a[IDX(i,i)]);
    }
    #pragma unroll
    for (int i=11;i>=0;i--){
      float s = y[i];
      #pragma unroll
      for (int k=11;k>i;k--) s = fmaf(-a[IDX(k,i)], Brow[k], s);
      Brow[i] = s * __builtin_amdgcn_rcpf(a[IDX(i,i)]);
    }
    {
      float mxv = 0.f;
      #pragma unroll
      for (int i=0;i<12;i++) mxv = fmaxf(mxv, fabsf(Brow[i]));
      mxv = fmaxf(mxv, __shfl_xor(mxv,1)); mxv = fmaxf(mxv, __shfl_xor(mxv,2));
      mxv = fmaxf(mxv, __shfl_xor(mxv,4)); mxv = fmaxf(mxv, __shfl_xor(mxv,8));
      float sc = __builtin_amdgcn_rcpf(mxv);
      #pragma unroll
      for (int i=0;i<12;i++) Brow[i] *= sc;
    }
    #pragma unroll
    for (int rep=0; rep<2; ++rep){                   // B -> B^2 -> B^4
      float nr[12];
      #pragma unroll
      for (int i=0;i<12;i++) nr[i]=0.f;
      #pragma unroll
      for (int k=0;k<12;k++){
        float bjk = Brow[k];
        #pragma unroll
        for (int m2=0;m2<12;m2++){
          float bkm = __shfl(Brow[m2], k);
          nr[m2] = fmaf(bjk, bkm, nr[m2]);
        }
      }
      float mxv = 0.f;
      #pragma unroll
      for (int i=0;i<12;i++) mxv = fmaxf(mxv, fabsf(nr[i]));
      mxv = fmaxf(mxv, __shfl_xor(mxv,1)); mxv = fmaxf(mxv, __shfl_xor(mxv,2));
      mxv = fmaxf(mxv, __shfl_xor(mxv,4)); mxv = fmaxf(mxv, __shfl_xor(mxv,8));
      float sc = __builtin_amdgcn_rcpf(mxv);
      #pragma unroll
      for (int i=0;i<12;i++) Brow[i] = nr[i]*sc;
    }
    float v = 0.f;
    #pragma unroll
    for (int i=0;i<12;i++) v += Brow[i];
    #pragma unroll
    for (int it=0; it<14; ++it){
      float w = 0.f;
      #pragma unroll
      for (int k=0;k<12;k++) w = fmaf(Brow[k], __shfl(v,k), w);
      float nn = w*w;
      nn += __shfl_xor(nn,1); nn += __shfl_xor(nn,2);
      nn += __shfl_xor(nn,4); nn += __shfl_xor(nn,8);
      v = w * rsqrtf(nn);
    }
    float pvf[12];
    #pragma unroll
    for (int i=0;i<12;i++) pvf[i] = __shfl(v, i);

    if (t==0){
      double pv[12];
      #pragma unroll
      for (int i=0;i<12;i++) pv[i]=(double)pvf[i];
      if (pv[10]<0.0){
        #pragma unroll
        for (int i=0;i<12;i++) pv[i]=-pv[i];
      }
      double nrm = sqrt(pv[8]*pv[8]+pv[9]*pv[9]+pv[10]*pv[10]);
      #pragma unroll
      for (int i=0;i<12;i++) pv[i]/=nrm;
      double m1[3]={sst[0],sst[1],sst[2]}, sd1[3]={sst[3],sst[4],sst[5]};
      double m2[3]={sst[6],sst[7],sst[8]}, sd2[3]={sst[9],sst[10],sst[11]};
      double Td[3][4]={{pv[0],pv[1],pv[2],pv[3]},
                       {pv[4],pv[5],pv[6],pv[7]},
                       {pv[8],pv[9],pv[10],pv[11]}};
      double F[3][4];
      for (int i=0;i<3;i++){
        double b3 = Td[i][3];
        for (int j=0;j<3;j++){
          F[i][j] = sd2[i]*(Td[i][j]/sd1[j]);        // inv(T2) @ Tdlt @ T1
          b3 += Td[i][j]*(-m1[j]/sd1[j]);
        }
        F[i][3] = sd2[i]*b3 + m2[i];
      }
      double zx=F[0][2],zy=F[1][2],zz2=F[2][2];
      double zn=sqrt(zx*zx+zy*zy+zz2*zz2);
      zx/=zn; zy/=zn; zz2/=zn;
      double yx=F[0][1],yy=F[1][1],yz=F[2][1];
      double xx=yy*zz2-yz*zy, xy=yz*zx-yx*zz2, xz=yx*zy-yy*zx;
      double xn=sqrt(xx*xx+xy*xy+xz*xz);
      xx/=xn; xy/=xn; xz/=xn;
      double y2x=zy*xz-zz2*xy, y2y=zz2*xx-zx*xz, y2z=zx*xy-zy*xx;
      double R00=xx,R01=y2x,R02=zx;
      double R10=xy,R11=y2y,R12=zy;
      double R20=xz,R21=y2z,R22=zz2;
      float* oT = out + b*16;
      oT[0]=(float)R00; oT[1]=(float)R01; oT[2]=(float)R02; oT[3]=(float)F[0][3];
      oT[4]=(float)R10; oT[5]=(float)R11; oT[6]=(float)R12; oT[7]=(float)F[1][3];
      oT[8]=(float)R20; oT[9]=(float)R21; oT[10]=(float)R22; oT[11]=(float)F[2][3];
      oT[12]=0.f; oT[13]=0.f; oT[14]=0.f; oT[15]=1.f;
      double qw=0.5*sqrt(fmax(1e-12, 1.0+R00+R11+R22));
      double qx=0.5*sqrt(fmax(0.0, 1.0+R00-R11-R22));
      double qy=0.5*sqrt(fmax(0.0, 1.0-R00+R11-R22));
      double qz=0.5*sqrt(fmax(0.0, 1.0-R00-R11+R22));
      if (R21-R12<0.0) qx=-qx;
      if (R02-R20<0.0) qy=-qy;
      if (R10-R01<0.0) qz=-qz;
      float* oQ = out + 128 + b*4;
      oQ[0]=(float)qw; oQ[1]=(float)qx; oQ[2]=(float)qy; oQ[3]=(float)qz;
      float* ot3 = out + 160 + b*3;
      ot3[0]=(float)F[0][3]; ot3[1]=(float)F[1][3]; ot3[2]=(float)F[2][3];
    }
  }
}

extern "C" void kernel_launch(void* const* d_in, const int* in_sizes, int n_in,
                              void* d_out, int out_size, void* d_ws, size_t ws_size,
                              hipStream_t stream) {
  const float* pc1 = (const float*)d_in[0];
  const float* pc2 = (const float*)d_in[1];
  float* out  = (float*)d_out;
  float* ws   = (float*)d_ws;

  // part4: 8*16*4096 float4 = 2,097,152 floats (8.4MB); partZ: 524,288 floats (2.1MB)
  float4* part4 = (float4*)ws;
  float*  partZ = ws + 4*2097152/4 + 0;              // after 2,097,152 floats
  partZ = ws + 2097152;

  hipLaunchKernelGGL(k_soft, dim3(2048), dim3(256), 0, stream, pc1, pc2, part4, partZ);
  hipLaunchKernelGGL(k_tail, dim3(8),    dim3(512), 0, stream, pc1, part4, partZ, out);
}

// Round 9
// 169.141 us; speedup vs baseline: 1.1535x; 1.0093x over previous
//
#include <hip/hip_runtime.h>
#include <math.h>

#define NPTS 4096
#define EPSC 1e-5f
#define F2C (2.0f*1.44269504088896340736f)

#if __has_builtin(__builtin_amdgcn_exp2f)
#define FEXP2 __builtin_amdgcn_exp2f
#else
#define FEXP2(x) __expf((x)*0.6931471805599453f)
#endif

#define IDX(i,j) ((i)*((i)+1)/2 + (j))   // packed lower-tri, i>=j

// one thread = one pc1 row; one block = (sample, 256-row block, 256-col chunk)
// pc2 chunk staged in LDS; ONLINE softmax (single pass, deferred per-wave rescale).
__global__ void __launch_bounds__(256) k_soft(const float* __restrict__ pc1,
                                              const float* __restrict__ pc2,
                                              float4* __restrict__ part4,
                                              float* __restrict__ partZ){
  constexpr int CHN = 256, NC = 16;
  int bid = blockIdx.x;                          // 2048 blocks
  int chunk = bid & (NC-1), rb = (bid/NC) & 15, b = bid/(NC*16);

  __shared__ float4 sp[CHN];                     // 4KB
  {
    const float* p2 = pc2 + (size_t)b*4*NPTS + chunk*CHN;
    for (int m = threadIdx.x; m < CHN; m += 256){
      float x = p2[m], y = p2[m+NPTS], z = p2[m+2*NPTS];
      sp[m] = make_float4(x, y, z, x*x + y*y + z*z);
    }
  }
  __syncthreads();

  int n = rb*256 + threadIdx.x;
  const float* p1 = pc1 + (size_t)b*4*NPTS + n;
  float x1 = p1[0], y1 = p1[NPTS], z1 = p1[2*NPTS];
  float q1 = x1*x1 + y1*y1 + z1*z1;
  float mx = -2.f*x1, my = -2.f*y1, mz = -2.f*z1;

  float4 c0 = sp[0];
  float d0 = fmaf(mx,c0.x, fmaf(my,c0.y, fmaf(mz,c0.z, c0.w + q1)));
  float m_ = F2C * __builtin_amdgcn_rcpf(fmaxf(d0, EPSC));   // running max (log2 units)
  float L = 1.f, Ax = c0.x, Ay = c0.y, Az = c0.z;

  #pragma unroll 8
  for (int mm=1; mm<CHN; ++mm){
    float4 c = sp[mm];
    float d = fmaf(mx,c.x, fmaf(my,c.y, fmaf(mz,c.z, c.w + q1)));
    float dinv = __builtin_amdgcn_rcpf(fmaxf(d, EPSC));
    float t = fmaf(F2C, dinv, -m_);              // s - m
    if (__any(t > 0.f)){                         // wave-uniform rescale (rare)
      float tp = fmaxf(t, 0.f);
      float sc = FEXP2(-tp);
      L *= sc; Ax *= sc; Ay *= sc; Az *= sc;
      m_ += tp;
      t = fminf(t, 0.f);                         // s - m_new
    }
    float pe = FEXP2(t);
    L += pe;
    Ax = fmaf(pe,c.x,Ax); Ay = fmaf(pe,c.y,Ay); Az = fmaf(pe,c.z,Az);
  }
  size_t idx = (size_t)(b*NC + chunk)*NPTS + n;
  part4[idx] = make_float4(m_, L, Ax, Ay);
  partZ[idx] = Az;
}

// 128 blocks x 256 thr, one thread per row: merge 16 chunk-partials ->
// rowdat (px,py,pz,dd) + per-block 13-sum partials.
__global__ void __launch_bounds__(256) k_mid(const float* __restrict__ pc1,
                                             const float4* __restrict__ part4,
                                             const float* __restrict__ partZ,
                                             float4* __restrict__ rowdat,
                                             float* __restrict__ psum13){
  constexpr int NC = 16;
  int b = blockIdx.x >> 4, rb = blockIdx.x & 15, t = threadIdx.x;
  int n = rb*256 + t;
  float4 f[NC]; float zz[NC];
  #pragma unroll
  for (int c=0;c<NC;c++){
    size_t idx = (size_t)(b*NC + c)*NPTS + n;
    f[c]  = part4[idx];
    zz[c] = partZ[idx];
  }
  float S = f[0].x;
  #pragma unroll
  for (int c=1;c<NC;c++) S = fmaxf(S, f[c].x);
  float L=0.f, Ax=0.f, Ay=0.f, Az=0.f;
  #pragma unroll
  for (int c=0;c<NC;c++){
    float w = FEXP2(f[c].x - S);
    L  = fmaf(w, f[c].y, L);
    Ax = fmaf(w, f[c].z, Ax);
    Ay = fmaf(w, f[c].w, Ay);
    Az = fmaf(w, zz[c],  Az);
  }
  float inv = 1.f/L;
  float px=Ax*inv, py=Ay*inv, pz=Az*inv;
  const float* p1 = pc1 + (size_t)b*4*NPTS + n;
  float x1=p1[0], y1=p1[NPTS], z1=p1[2*NPTS];
  float dx=x1-px, dy=y1-py, dz=z1-pz;
  float dd=sqrtf(dx*dx+dy*dy+dz*dz);
  rowdat[(size_t)b*NPTS + n] = make_float4(px,py,pz,dd);

  float acc[13]={x1,y1,z1,x1*x1,y1*y1,z1*z1,px,py,pz,px*px,py*py,pz*pz,dd};
  __shared__ float red[4][13];
  int lane = t & 63, wv = t >> 6;
  #pragma unroll
  for (int k=0;k<13;k++){
    float v = acc[k];
    v += __shfl_xor(v,32); v += __shfl_xor(v,16); v += __shfl_xor(v,8);
    v += __shfl_xor(v,4);  v += __shfl_xor(v,2);  v += __shfl_xor(v,1);
    if (lane==0) red[wv][k]=v;
  }
  __syncthreads();
  if (t<13)
    psum13[(size_t)blockIdx.x*13 + t] = red[0][t]+red[1][t]+red[2][t]+red[3][t];
}

__device__ __forceinline__ void stats_from_tot(const float* stot, float* sst){
  const float Nf = 4096.f, Nm1 = 4095.f;
  #pragma unroll
  for (int j=0;j<3;j++){
    float m  = stot[j]/Nf;
    float v  = (stot[3+j]-Nf*m*m)/Nm1;             // ddof=1
    sst[j]=m; sst[3+j]=sqrtf(fmaxf(v,0.f));
    float m2 = stot[6+j]/Nf;
    float v2 = (stot[9+j]-Nf*m2*m2)/Nm1;
    sst[6+j]=m2; sst[9+j]=sqrtf(fmaxf(v2,0.f));
  }
  sst[12]=stot[12]/Nf;
}

__device__ __forceinline__ float elemA(const float* S, int i, int k){
  int bi=i>>2, bj=k>>2;
  int ii=i&3, jj=k&3;
  int lo = ii<jj?ii:jj, hi = ii<jj?jj:ii;
  int pe = 4*lo - ((lo*(lo-1))>>1) + (hi-lo);        // sym 4x4 -> 10 idx
  int w;
  if (bi==bj) w = (bi==2)?30:0;
  else {
    int blo = bi<bj?bi:bj, bhi = bi<bj?bj:bi;
    if (blo==0 && bhi==1) return 0.f;                // A01 block is zero
    w = (blo==0)?10:20;                              // (0,2)->wB, (1,2)->wC
  }
  return S[w+pe];
}

// 8 blocks x 1024 thr: psum13 reduce -> stats -> masked M^T M 40-sums ->
// wave 0 register Cholesky inverse-power eigensolve + compose.
__global__ void __launch_bounds__(1024) k_fin(const float* __restrict__ pc1,
                                              const float4* __restrict__ rowdat,
                                              const float* __restrict__ psum13,
                                              float* __restrict__ out){
  int b = blockIdx.x, t = threadIdx.x;
  int lane = t & 63, wv = t >> 6;                    // 16 waves

  __shared__ float stot[13];
  __shared__ float sst[13];
  __shared__ float red40[16][40];
  __shared__ float SS[40];

  if (t<13){
    float s=0.f;
    #pragma unroll
    for (int i=0;i<16;i++) s += psum13[(size_t)(b*16+i)*13 + t];
    stot[t]=s;
  }
  __syncthreads();
  if (t==0) stats_from_tot(stot, sst);
  __syncthreads();

  float i1x=1.f/sst[3], i1y=1.f/sst[4], i1z=1.f/sst[5];
  float t1x=-sst[0]/sst[3], t1y=-sst[1]/sst[4], t1z=-sst[2]/sst[5];
  float i2x=1.f/sst[9], i2y=1.f/sst[10], i2z=1.f/sst[11];
  float t2x=-sst[6]/sst[9], t2y=-sst[7]/sst[10], t2z=-sst[8]/sst[11];
  float meanD=sst[12];

  float acc[40];
  #pragma unroll
  for (int k=0;k<40;k++) acc[k]=0.f;
  #pragma unroll
  for (int i=0;i<4;i++){
    int n = i*1024 + t;
    const float* p1 = pc1 + (size_t)b*4*NPTS + n;
    float X1=fmaf(p1[0],i1x,t1x), Y1=fmaf(p1[NPTS],i1y,t1y), Z1=fmaf(p1[2*NPTS],i1z,t1z);
    float4 rd = rowdat[(size_t)b*NPTS + n];
    float X2=fmaf(rd.x,i2x,t2x);
    float Y2=fmaf(rd.y,i2y,t2y);
    float Z2=fmaf(rd.z,i2z,t2z);
    // sigmoid((dist-mean-EPS)*-1e10) > 0.5  <=>  (dist-mean)-EPS < 0
    float zthr = (rd.w - meanD) - EPSC;
    float msk = (zthr < 0.f) ? 1.f : 0.f;
    float tz = msk*Z2;
    float wA = tz*Z2, wB = -tz*X2, wC = -tz*Y2;
    float wD = msk*fmaf(X2,X2,Y2*Y2);
    float ee[10]={X1*X1, X1*Y1, X1*Z1, X1, Y1*Y1, Y1*Z1, Y1, Z1*Z1, Z1, 1.f};
    #pragma unroll
    for (int j=0;j<10;j++){
      acc[j]    = fmaf(wA,ee[j],acc[j]);
      acc[10+j] = fmaf(wB,ee[j],acc[10+j]);
      acc[20+j] = fmaf(wC,ee[j],acc[20+j]);
      acc[30+j] = fmaf(wD,ee[j],acc[30+j]);
    }
  }
  #pragma unroll
  for (int k=0;k<40;k++){
    float v=acc[k];
    v+=__shfl_xor(v,32); v+=__shfl_xor(v,16); v+=__shfl_xor(v,8);
    v+=__shfl_xor(v,4);  v+=__shfl_xor(v,2);  v+=__shfl_xor(v,1);
    if(lane==0) red40[wv][k]=v;
  }
  __syncthreads();
  if (t<40){
    float s=0.f;
    #pragma unroll
    for (int w=0;w<16;w++) s += red40[w][t];
    SS[t]=s;
  }
  __syncthreads();

  if (t<64){
    float a[78];
    #pragma unroll
    for (int i=0;i<12;i++)
      #pragma unroll
      for (int j=0;j<=i;j++)
        a[IDX(i,j)] = elemA(SS,i,j);
    {
      float tr=0.f;
      #pragma unroll
      for (int i=0;i<12;i++) tr += a[IDX(i,i)];
      float eps = 1e-5f * tr * (1.f/12.f);           // uniform shift: eigvecs unchanged
      #pragma unroll
      for (int i=0;i<12;i++) a[IDX(i,i)] += eps;
    }
    #pragma unroll
    for (int j=0;j<12;j++){
      float s = a[IDX(j,j)];
      #pragma unroll
      for (int k=0;k<j;k++) s = fmaf(-a[IDX(j,k)], a[IDX(j,k)], s);
      float d = sqrtf(fmaxf(s, 1e-30f));
      a[IDX(j,j)] = d;
      float dinv = __builtin_amdgcn_rcpf(d);
      #pragma unroll
      for (int i=j+1;i<12;i++){
        float s2 = a[IDX(i,j)];
        #pragma unroll
        for (int k=0;k<j;k++) s2 = fmaf(-a[IDX(i,k)], a[IDX(j,k)], s2);
        a[IDX(i,j)] = s2 * dinv;
      }
    }
    // lane j: solve (A+eps I) x = e_j -> column j of B
    float y[12], Brow[12];
    #pragma unroll
    for (int i=0;i<12;i++){
      float s = (i==t) ? 1.f : 0.f;
      #pragma unroll
      for (int k=0;k<i;k++) s = fmaf(-a[IDX(i,k)], y[k], s);
      y[i] = s * __builtin_amdgcn_rcpf(a[IDX(i,i)]);
    }
    #pragma unroll
    for (int i=11;i>=0;i--){
      float s = y[i];
      #pragma unroll
      for (int k=11;k>i;k--) s = fmaf(-a[IDX(k,i)], Brow[k], s);
      Brow[i] = s * __builtin_amdgcn_rcpf(a[IDX(i,i)]);
    }
    {
      float mxv = 0.f;
      #pragma unroll
      for (int i=0;i<12;i++) mxv = fmaxf(mxv, fabsf(Brow[i]));
      mxv = fmaxf(mxv, __shfl_xor(mxv,1)); mxv = fmaxf(mxv, __shfl_xor(mxv,2));
      mxv = fmaxf(mxv, __shfl_xor(mxv,4)); mxv = fmaxf(mxv, __shfl_xor(mxv,8));
      float sc = __builtin_amdgcn_rcpf(mxv);
      #pragma unroll
      for (int i=0;i<12;i++) Brow[i] *= sc;
    }
    #pragma unroll
    for (int rep=0; rep<2; ++rep){                   // B -> B^2 -> B^4
      float nr[12];
      #pragma unroll
      for (int i=0;i<12;i++) nr[i]=0.f;
      #pragma unroll
      for (int k=0;k<12;k++){
        float bjk = Brow[k];
        #pragma unroll
        for (int m2=0;m2<12;m2++){
          float bkm = __shfl(Brow[m2], k);
          nr[m2] = fmaf(bjk, bkm, nr[m2]);
        }
      }
      float mxv = 0.f;
      #pragma unroll
      for (int i=0;i<12;i++) mxv = fmaxf(mxv, fabsf(nr[i]));
      mxv = fmaxf(mxv, __shfl_xor(mxv,1)); mxv = fmaxf(mxv, __shfl_xor(mxv,2));
      mxv = fmaxf(mxv, __shfl_xor(mxv,4)); mxv = fmaxf(mxv, __shfl_xor(mxv,8));
      float sc = __builtin_amdgcn_rcpf(mxv);
      #pragma unroll
      for (int i=0;i<12;i++) Brow[i] = nr[i]*sc;
    }
    float v = 0.f;
    #pragma unroll
    for (int i=0;i<12;i++) v += Brow[i];
    #pragma unroll
    for (int it=0; it<14; ++it){
      float w = 0.f;
      #pragma unroll
      for (int k=0;k<12;k++) w = fmaf(Brow[k], __shfl(v,k), w);
      float nn = w*w;
      nn += __shfl_xor(nn,1); nn += __shfl_xor(nn,2);
      nn += __shfl_xor(nn,4); nn += __shfl_xor(nn,8);
      v = w * rsqrtf(nn);
    }
    float pvf[12];
    #pragma unroll
    for (int i=0;i<12;i++) pvf[i] = __shfl(v, i);

    if (t==0){
      double pv[12];
      #pragma unroll
      for (int i=0;i<12;i++) pv[i]=(double)pvf[i];
      if (pv[10]<0.0){
        #pragma unroll
        for (int i=0;i<12;i++) pv[i]=-pv[i];
      }
      double nrm = sqrt(pv[8]*pv[8]+pv[9]*pv[9]+pv[10]*pv[10]);
      #pragma unroll
      for (int i=0;i<12;i++) pv[i]/=nrm;
      double m1[3]={sst[0],sst[1],sst[2]}, sd1[3]={sst[3],sst[4],sst[5]};
      double m2[3]={sst[6],sst[7],sst[8]}, sd2[3]={sst[9],sst[10],sst[11]};
      double Td[3][4]={{pv[0],pv[1],pv[2],pv[3]},
                       {pv[4],pv[5],pv[6],pv[7]},
                       {pv[8],pv[9],pv[10],pv[11]}};
      double F[3][4];
      for (int i=0;i<3;i++){
        double b3 = Td[i][3];
        for (int j=0;j<3;j++){
          F[i][j] = sd2[i]*(Td[i][j]/sd1[j]);        // inv(T2) @ Tdlt @ T1
          b3 += Td[i][j]*(-m1[j]/sd1[j]);
        }
        F[i][3] = sd2[i]*b3 + m2[i];
      }
      double zx=F[0][2],zy=F[1][2],zz2=F[2][2];
      double zn=sqrt(zx*zx+zy*zy+zz2*zz2);
      zx/=zn; zy/=zn; zz2/=zn;
      double yx=F[0][1],yy=F[1][1],yz=F[2][1];
      double xx=yy*zz2-yz*zy, xy=yz*zx-yx*zz2, xz=yx*zy-yy*zx;
      double xn=sqrt(xx*xx+xy*xy+xz*xz);
      xx/=xn; xy/=xn; xz/=xn;
      double y2x=zy*xz-zz2*xy, y2y=zz2*xx-zx*xz, y2z=zx*xy-zy*xx;
      double R00=xx,R01=y2x,R02=zx;
      double R10=xy,R11=y2y,R12=zy;
      double R20=xz,R21=y2z,R22=zz2;
      float* oT = out + b*16;
      oT[0]=(float)R00; oT[1]=(float)R01; oT[2]=(float)R02; oT[3]=(float)F[0][3];
      oT[4]=(float)R10; oT[5]=(float)R11; oT[6]=(float)R12; oT[7]=(float)F[1][3];
      oT[8]=(float)R20; oT[9]=(float)R21; oT[10]=(float)R22; oT[11]=(float)F[2][3];
      oT[12]=0.f; oT[13]=0.f; oT[14]=0.f; oT[15]=1.f;
      double qw=0.5*sqrt(fmax(1e-12, 1.0+R00+R11+R22));
      double qx=0.5*sqrt(fmax(0.0, 1.0+R00-R11-R22));
      double qy=0.5*sqrt(fmax(0.0, 1.0-R00+R11-R22));
      double qz=0.5*sqrt(fmax(0.0, 1.0-R00-R11+R22));
      if (R21-R12<0.0) qx=-qx;
      if (R02-R20<0.0) qy=-qy;
      if (R10-R01<0.0) qz=-qz;
      float* oQ = out + 128 + b*4;
      oQ[0]=(float)qw; oQ[1]=(float)qx; oQ[2]=(float)qy; oQ[3]=(float)qz;
      float* ot3 = out + 160 + b*3;
      ot3[0]=(float)F[0][3]; ot3[1]=(float)F[1][3]; ot3[2]=(float)F[2][3];
    }
  }
}

extern "C" void kernel_launch(void* const* d_in, const int* in_sizes, int n_in,
                              void* d_out, int out_size, void* d_ws, size_t ws_size,
                              hipStream_t stream) {
  const float* pc1 = (const float*)d_in[0];
  const float* pc2 = (const float*)d_in[1];
  float* out  = (float*)d_out;
  float* ws   = (float*)d_ws;

  // floats: part4 2,097,152 | partZ 524,288 | rowdat 131,072 | psum13 1,664
  // total 2,754,176 floats = 11,016,704 B (== proven-available from round 3)
  float4* part4  = (float4*)ws;
  float*  partZ  = ws + 2097152;
  float4* rowdat = (float4*)(ws + 2097152 + 524288);
  float*  psum13 = ws + 2097152 + 524288 + 131072;

  hipLaunchKernelGGL(k_soft, dim3(2048), dim3(256),  0, stream, pc1, pc2, part4, partZ);
  hipLaunchKernelGGL(k_mid,  dim3(128),  dim3(256),  0, stream, pc1, part4, partZ, rowdat, psum13);
  hipLaunchKernelGGL(k_fin,  dim3(8),    dim3(1024), 0, stream, pc1, rowdat, psum13, out);
}